// Round 6
// baseline (2691.769 us; speedup 1.0000x reference)
//
#include <hip/hip_runtime.h>
#include <math.h>

// ---------------- constants ----------------
static constexpr int B_   = 128;
static constexpr int ORG_ = 4;
static constexpr int L_   = 2048;
static constexpr int C1_  = 128;
static constexpr int C2_  = 64;
static constexpr int NG_  = 8;
static constexpr int VQD_ = 64;
static constexpr int VQN_ = 1024;

typedef __attribute__((ext_vector_type(8))) short bf16x8;
typedef __attribute__((ext_vector_type(4))) float f32x4;

__device__ __forceinline__ float selu_f(float x) {
    const float scale = 1.0507009873554805f;
    const float alpha = 1.6732632423543772f;
    return scale * (x > 0.f ? x : alpha * expm1f(x));
}
__device__ __forceinline__ unsigned short f2bf(float x) {
    unsigned u = __float_as_uint(x);
    u = (u + 0x7FFFu + ((u >> 16) & 1u)) >> 16;
    return (unsigned short)u;
}

// ---------------- weight prep (f32 direct-conv layout) ----------------
__global__ void wprep_kernel(const float* __restrict__ w, float* __restrict__ wT,
                             int CO, int cig, int K, int so, int si, int sk, int koff)
{
    int idx = blockIdx.x * 256 + threadIdx.x;
    int total = cig * K * CO;
    if (idx >= total) return;
    int o = idx % CO;
    int r = idx / CO;
    int i = r / K, k = r % K;
    wT[idx] = w[(long)o * so + (long)i * si + (long)k * sk + koff];
}

// ---------------- weight prep (MFMA bf16 layout) for tconv 128x128 K=5 ----------------
// wb[((k*16 + ic*4 + ig)*128 + o)*8 + j] = bf16( w[i][o][4-k] ), i = ic*32 + ig*8 + j
__global__ void wprep_mfma_kernel(const float* __restrict__ w, unsigned short* __restrict__ wb)
{
    int idx = blockIdx.x * 256 + threadIdx.x;   // total 81920
    if (idx >= 5 * 16 * 128 * 8) return;
    int j  = idx & 7;
    int o  = (idx >> 3) & 127;
    int kk = idx >> 10;          // 0..79
    int ig = kk & 3, ic = (kk >> 2) & 3, k = kk >> 4;
    int i  = ic * 32 + ig * 8 + j;
    wb[idx] = f2bf(w[(long)i * (128 * 5) + o * 5 + (4 - k)]);
}

// ---------------- LDS-tiled f32 conv with optional fused input transform ----------------
// OT outputs (consecutive o) per thread; NT consecutive t per thread.
template<int K, int CO, int NTHR, int TT, int OT>
__global__ __launch_bounds__(NTHR) void conv_tile_kernel(
    const float* __restrict__ in, const float* __restrict__ wT,
    const float* __restrict__ scale, const float* __restrict__ bias,
    float* __restrict__ out,
    int CI, int T, int cig, int cog,
    const float* __restrict__ ist, const float* __restrict__ ig,
    const float* __restrict__ ibt, int icpg, int iselu,
    const float* __restrict__ res)
{
    constexpr int P    = (K - 1) / 2;
    constexpr int SPAN = TT + K - 1;
    constexpr int RS   = (SPAN + 3) & ~3;
    constexpr int NO   = CO / OT;                 // thread-groups in o
    constexpr int NT   = (CO * TT) / (NTHR * OT);
    constexpr int XW   = NT + K - 1;
    extern __shared__ float lds[];

    const int tile = blockIdx.x;
    const int b    = blockIdx.y;
    const int t0g  = tile * TT;
    const float* inb = in + (long)b * CI * T;

    for (int idx = threadIdx.x; idx < CI * SPAN; idx += NTHR) {
        int c = idx / SPAN, j = idx % SPAN;
        int tt = t0g + j - P;
        float v = 0.f;
        if (tt >= 0 && tt < T) {
            v = inb[(long)c * T + tt];
            if (ist) {
                const float* s = &ist[2 * (b * NG_ + c / icpg)];
                v = (v - s[0]) * s[1] * ig[c] + ibt[c];
                if (res) v += res[((long)b * CI + c) * T + tt];
                if (iselu) v = selu_f(v);
            }
        }
        lds[c * RS + j] = v;
    }
    __syncthreads();

    const int o0   = (threadIdx.x % NO) * OT;
    const int slot = threadIdx.x / NO;
    const int t0   = slot * NT;
    const int g    = o0 / cog;                    // OT never straddles groups here
    const float* wrow = wT + o0;

    float acc[OT][NT];
#pragma unroll
    for (int oo = 0; oo < OT; ++oo)
#pragma unroll
        for (int u = 0; u < NT; ++u) acc[oo][u] = 0.f;

    for (int i = 0; i < cig; ++i) {
        const int irow = g * cig + i;
        float xin[(XW + 3) & ~3];
        if constexpr (NT % 4 == 0) {
            constexpr int X4 = (XW + 3) / 4;
            const float4* l4 = reinterpret_cast<const float4*>(&lds[irow * RS + t0]);
#pragma unroll
            for (int j = 0; j < X4; ++j) {
                float4 v = l4[j];
                xin[4 * j]     = v.x;
                xin[4 * j + 1] = v.y;
                xin[4 * j + 2] = v.z;
                xin[4 * j + 3] = v.w;
            }
        } else {
#pragma unroll
            for (int j = 0; j < XW; ++j) xin[j] = lds[irow * RS + t0 + j];
        }
        float wk[OT][K];
#pragma unroll
        for (int oo = 0; oo < OT; ++oo)
#pragma unroll
            for (int k = 0; k < K; ++k) wk[oo][k] = wrow[(i * K + k) * CO + oo];
#pragma unroll
        for (int oo = 0; oo < OT; ++oo)
#pragma unroll
            for (int u = 0; u < NT; ++u)
#pragma unroll
                for (int k = 0; k < K; ++k)
                    acc[oo][u] = fmaf(xin[u + k], wk[oo][k], acc[oo][u]);
    }

#pragma unroll
    for (int oo = 0; oo < OT; ++oo) {
        const int o = o0 + oo;
        const float sc = scale ? scale[o] : 1.f;
        const float bi = bias  ? bias[o]  : 0.f;
        float* ob = out + ((long)b * CO + o) * T + t0g + t0;
#pragma unroll
        for (int u = 0; u < NT; ++u) ob[u] = acc[oo][u] * sc + bi;
    }
}

// ---------------- MFMA bf16 conv: CI=128, CO=128, K=5 (decoder deres1) ----------------
__global__ __launch_bounds__(256) void conv_mfma5_kernel(
    const float* __restrict__ in, const unsigned short* __restrict__ wb,
    float* __restrict__ out, int T,
    const float* __restrict__ ist, const float* __restrict__ ig_,
    const float* __restrict__ ibt, int icpg)
{
    constexpr int SPAN = 68, RSI = 136;
    __shared__ unsigned short xlds[SPAN * RSI];   // 18.5 KB

    const int t0g = blockIdx.x * 64;
    const int b   = blockIdx.y;
    const float* inb = in + (long)b * 128 * T;

    for (int idx = threadIdx.x; idx < 128 * SPAN; idx += 256) {
        int i = idx / SPAN, j = idx % SPAN;
        int tt = t0g + j - 2;
        float v = 0.f;
        if (tt >= 0 && tt < T) {
            v = inb[(long)i * T + tt];
            if (ist) {
                const float* s = &ist[2 * (b * NG_ + i / icpg)];
                v = selu_f((v - s[0]) * s[1] * ig_[i] + ibt[i]);
            }
        }
        xlds[j * RSI + i] = f2bf(v);
    }
    __syncthreads();

    const int lane = threadIdx.x & 63;
    const int wid  = threadIdx.x >> 6;
    const int tw   = wid * 16;
    const int mr   = lane & 15;
    const int kg   = lane >> 4;

    f32x4 acc[8];
#pragma unroll
    for (int ot = 0; ot < 8; ++ot) acc[ot] = (f32x4){0.f, 0.f, 0.f, 0.f};

#pragma unroll
    for (int k = 0; k < 5; ++k) {
#pragma unroll
        for (int ic = 0; ic < 4; ++ic) {
            bf16x8 a = *(const bf16x8*)&xlds[(tw + mr + k) * RSI + ic * 32 + kg * 8];
            const unsigned short* wp = wb + (((k * 16 + ic * 4 + kg) * 128) + mr) * 8;
#pragma unroll
            for (int ot = 0; ot < 8; ++ot) {
                bf16x8 bfr = *(const bf16x8*)(wp + ot * 16 * 8);
                acc[ot] = __builtin_amdgcn_mfma_f32_16x16x32_bf16(a, bfr, acc[ot], 0, 0, 0);
            }
        }
    }

#pragma unroll
    for (int ot = 0; ot < 8; ++ot) {
        int o = ot * 16 + mr;
        float4 v = make_float4(acc[ot][0], acc[ot][1], acc[ot][2], acc[ot][3]);
        *(float4*)&out[((long)b * 128 + o) * T + t0g + tw + kg * 4] = v;
    }
}

// ---------------- GroupNorm stats ----------------
__global__ __launch_bounds__(256) void gn_stats_kernel(
    const float* __restrict__ x, float* __restrict__ stats,
    int C, int T, int G)
{
    const int bg = blockIdx.x;
    const int cpg = C / G;
    const int b = bg / G, g = bg % G;
    const float* base = x + ((long)b * C + (long)g * cpg) * T;
    const long n4 = (long)cpg * T / 4;
    const float4* b4 = (const float4*)base;
    float s = 0.f, ss = 0.f;
    for (long i = threadIdx.x; i < n4; i += blockDim.x) {
        float4 v = b4[i];
        s += v.x + v.y + v.z + v.w;
        ss += v.x * v.x + v.y * v.y + v.z * v.z + v.w * v.w;
    }
#pragma unroll
    for (int off = 32; off; off >>= 1) {
        s  += __shfl_down(s, off);
        ss += __shfl_down(ss, off);
    }
    __shared__ float sh_s[4], sh_ss[4];
    const int wid = threadIdx.x >> 6, lane = threadIdx.x & 63;
    if (lane == 0) { sh_s[wid] = s; sh_ss[wid] = ss; }
    __syncthreads();
    if (threadIdx.x == 0) {
        float S = 0.f, SS = 0.f;
        for (int i = 0; i < 4; ++i) { S += sh_s[i]; SS += sh_ss[i]; }
        float inv_n = 1.f / (float)((long)cpg * T);
        float mu  = S * inv_n;
        float var = SS * inv_n - mu * mu;
        stats[2 * bg]     = mu;
        stats[2 * bg + 1] = rsqrtf(var + 1e-5f);
    }
}

// ---------------- fused: out = maxpool2( selu( T1(x) + T2(r) ) ) ----------------
__global__ __launch_bounds__(256) void pool_fused_kernel(
    const float* __restrict__ x, const float* __restrict__ xst,
    const float* __restrict__ xg, const float* __restrict__ xb, int xcpg,
    const float* __restrict__ r, const float* __restrict__ rst,
    const float* __restrict__ rg, const float* __restrict__ rb, int rcpg, int rselu,
    float* __restrict__ out, int C, int Tout, long total)
{
    for (long idx = blockIdx.x * (long)blockDim.x + threadIdx.x; idx < total;
         idx += (long)gridDim.x * blockDim.x) {
        const int to = (int)(idx % Tout);
        const int c  = (int)((idx / Tout) % C);
        const int b  = (int)(idx / ((long)Tout * C));
        const long base = ((long)b * C + c) * (2 * Tout);
        const float* sx = &xst[2 * (b * NG_ + c / xcpg)];
        const float xgc = sx[1] * xg[c], xbc = xb[c] - sx[0] * sx[1] * xg[c];
        float rgc = 1.f, rbc = 0.f;
        if (rst) {
            const float* sr = &rst[2 * (b * NG_ + c / rcpg)];
            rgc = sr[1] * rg[c]; rbc = rb[c] - sr[0] * sr[1] * rg[c];
        }
        float f[2];
#pragma unroll
        for (int q = 0; q < 2; ++q) {
            long t = base + 2 * to + q;
            float rv = r[t] * rgc + rbc;
            if (rst && rselu) rv = selu_f(rv);
            f[q] = selu_f(x[t] * xgc + xbc + rv);
        }
        out[((long)b * C + c) * Tout + to] = fmaxf(f[0], f[1]);
    }
}

// ---------------- fused: out = upsample2( selu( T(x) [+ res] ) ) ----------------
__global__ __launch_bounds__(256) void up_fused_kernel(
    const float* __restrict__ x, const float* __restrict__ xst,
    const float* __restrict__ xg, const float* __restrict__ xb, int xcpg,
    const float* __restrict__ res,
    float* __restrict__ out, int C, int Tin, long total)
{
    for (long idx = blockIdx.x * (long)blockDim.x + threadIdx.x; idx < total;
         idx += (long)gridDim.x * blockDim.x) {
        const int t = (int)(idx % Tin);
        const int c = (int)((idx / Tin) % C);
        const int b = (int)(idx / ((long)Tin * C));
        const float* s = &xst[2 * (b * NG_ + c / xcpg)];
        float v = (x[idx] - s[0]) * s[1] * xg[c] + xb[c];
        if (res) v += res[idx];
        v = selu_f(v);
        float2* o2 = (float2*)(out + (((long)b * C + c) * Tin + t) * 2);
        *o2 = make_float2(v, v);
    }
}

// ---------------- VQ ----------------
__global__ void wnorm_kernel(const float* __restrict__ codes, float* __restrict__ wn)
{
    int j = blockIdx.x * 256 + threadIdx.x;
    if (j >= VQN_) return;
    const float* c = codes + (long)j * VQD_;
    float s = 0.f;
#pragma unroll
    for (int i = 0; i < VQD_; ++i) s = fmaf(c[i], c[i], s);
    wn[j] = s;
}

// VQ v3: 64 points per block (one per lane); wave w scans codes [w*256,(w+1)*256).
// Scan ascending j with strict <, slices combined ascending -> argmin identical to r5.
// hq written cooperatively, t-coalesced. Loss recomputed from f32 h.
__global__ __launch_bounds__(256) void vq_kernel(
    const float* __restrict__ h, const float* __restrict__ codes,
    const float* __restrict__ wn, float* __restrict__ hq, float* __restrict__ loss,
    int T)
{
    const int lane = threadIdx.x & 63;
    const int w    = threadIdx.x >> 6;
    const int n0   = blockIdx.x * 64;
    const int b    = n0 / T;          // uniform per block (T multiple of 64)
    const int tb   = n0 % T;
    const int t    = tb + lane;

    float z[VQD_];
#pragma unroll
    for (int c = 0; c < VQD_; ++c) z[c] = h[((long)b * VQD_ + c) * T + t];

    float best = 3.4e38f;
    int bj = w * 256;
    for (int j = w * 256; j < w * 256 + 256; ++j) {
        const float4* cw4 = (const float4*)(codes + (long)j * VQD_);
        float dot = 0.f;
#pragma unroll
        for (int q = 0; q < VQD_ / 4; ++q) {
            float4 w4 = cw4[q];
            dot = fmaf(z[4 * q],     w4.x, dot);
            dot = fmaf(z[4 * q + 1], w4.y, dot);
            dot = fmaf(z[4 * q + 2], w4.z, dot);
            dot = fmaf(z[4 * q + 3], w4.w, dot);
        }
        float scv = wn[j] - 2.f * dot;
        if (scv < best) { best = scv; bj = j; }
    }

    __shared__ float sb[4][64];
    __shared__ int   sj[4][64];
    __shared__ int   sbj[64];
    sb[w][lane] = best; sj[w][lane] = bj;
    __syncthreads();
    if (w == 0) {
#pragma unroll
        for (int s = 1; s < 4; ++s)
            if (sb[s][lane] < best) { best = sb[s][lane]; bj = sj[s][lane]; }
        sbj[lane] = bj;
    }
    __syncthreads();

    // cooperative hq write (t-coalesced) + loss from f32 z
    float l = 0.f;
    for (int idx = threadIdx.x; idx < VQD_ * 64; idx += 256) {
        int c  = idx >> 6, tl = idx & 63;
        int jj = sbj[tl];
        float wv = codes[(long)jj * VQD_ + c];
        long off = ((long)b * VQD_ + c) * T + tb + tl;
        hq[off] = wv;
        float df = h[off] - wv;
        l = fmaf(df, df, l);
    }
#pragma unroll
    for (int off = 32; off; off >>= 1) l += __shfl_down(l, off);
    if (lane == 0) atomicAdd(loss, l);
}

__global__ void zero_kernel(float* p) { p[0] = 0.f; }

__global__ void finalize_kernel(const float* __restrict__ loss, float* __restrict__ out,
                                float invNP, long off)
{
    float v = loss[0] * invNP;
    out[off]     = v;
    out[off + 1] = v;
}

// ---------------- host side ----------------
static inline int nblk(long total, int thr = 256, long cap = 262144) {
    long b = (total + thr - 1) / thr;
    if (b > cap) b = cap;
    if (b < 1) b = 1;
    return (int)b;
}
static inline int ldsz(int CI, int K, int TT = 64) {
    int span = TT + K - 1;
    int rs = (span + 3) & ~3;
    return CI * rs * 4;
}

struct WT {
    long w0, wxa, wxb, wxc, w2, wd2, wd0, total;
};
static WT wt_offsets() {
    WT o; long p = 0;
    o.w0   = p; p += (long)ORG_ * 7 * C1_;
    o.wxa  = p; p += (long)C1_ * 1 * (C1_ / 2);
    o.wxb  = p; p += 2L * 5 * (C1_ / 2);
    o.wxc  = p; p += (long)(C1_ / 2) * 1 * C1_;
    o.w2   = p; p += (long)C1_ * 3 * C2_;
    o.wd2  = p; p += (long)C2_ * 3 * C1_;
    o.wd0  = p; p += (long)C1_ * 7 * ORG_;
    o.total = p;
    return o;
}

static void run_chunk(const float* x, const float* const* W, const float* wt,
                      const WT& wo, const unsigned short* wbA, const unsigned short* wbB,
                      const float* wn, float* out,
                      float* A, float* Bb, float* Cc, float* st, float* lossbuf,
                      int Bc, long nbuf, hipStream_t stream)
{
    const float* g0_g  = W[1];
    const float* g0_b  = W[2];
    const float* gxa_g = W[4];
    const float* gxa_b = W[5];
    const float* gxb_g = W[7];
    const float* gxb_b = W[8];
    const float* gxc_g = W[10];
    const float* gxc_b = W[11];
    const float* bn2_g = W[13];
    const float* bn2_b = W[14];
    const float* embed = W[15];
    const float* gd2_g = W[17];
    const float* gd2_b = W[18];
    const float* gd1a_g= W[20];
    const float* gd1a_b= W[21];
    const float* gd1b_g= W[23];
    const float* gd1b_b= W[24];
    const float* bd0   = W[26];

    const int D_ = C1_ / 2;  // 64
    const int SLOT = 2048;
    float* st0 = st + 0 * SLOT;
    float* st1 = st + 1 * SLOT;
    float* st2 = st + 2 * SLOT;
    float* st3 = st + 3 * SLOT;
    float* st4 = st + 4 * SLOT;
    float* st5 = st + 5 * SLOT;
    float* st6 = st + 6 * SLOT;

    int T = L_;  // 2048

    // ============ encoder (all f32, bit-stable for VQ argmin) ============
    conv_tile_kernel<7, 128, 512, 64, 1><<<dim3(T / 64, Bc), 512, ldsz(ORG_, 7), stream>>>(
        x, wt + wo.w0, nullptr, nullptr, A, ORG_, T, ORG_, C1_,
        nullptr, nullptr, nullptr, 0, 0, nullptr);
    gn_stats_kernel<<<Bc * NG_, 256, 0, stream>>>(A, st0, C1_, T, NG_);

    conv_tile_kernel<1, 64, 512, 64, 2><<<dim3(T / 64, Bc), 512, ldsz(C1_, 1), stream>>>(
        A, wt + wo.wxa, nullptr, nullptr, Bb, C1_, T, C1_, D_,
        st0, g0_g, g0_b, C1_ / NG_, 1, nullptr);
    gn_stats_kernel<<<Bc * NG_, 256, 0, stream>>>(Bb, st1, D_, T, NG_);

    conv_tile_kernel<5, 64, 512, 64, 1><<<dim3(T / 64, Bc), 512, ldsz(D_, 5), stream>>>(
        Bb, wt + wo.wxb, nullptr, nullptr, Bb + nbuf / 2, D_, T, 2, 2,
        st1, gxa_g, gxa_b, D_ / NG_, 1, nullptr);
    gn_stats_kernel<<<Bc * NG_, 256, 0, stream>>>(Bb + nbuf / 2, st2, D_, T, NG_);

    conv_tile_kernel<1, 128, 512, 64, 2><<<dim3(T / 64, Bc), 512, ldsz(D_, 1), stream>>>(
        Bb + nbuf / 2, wt + wo.wxc, nullptr, nullptr, Cc, D_, T, D_, C1_,
        st2, gxb_g, gxb_b, D_ / NG_, 1, nullptr);
    gn_stats_kernel<<<Bc * NG_, 256, 0, stream>>>(Cc, st3, C1_, T, NG_);

    {
        int Tout = T / 2;
        long tt = (long)Bc * C1_ * Tout;
        pool_fused_kernel<<<nblk(tt), 256, 0, stream>>>(
            Cc, st3, gxc_g, gxc_b, C1_ / NG_,
            A, st0, g0_g, g0_b, C1_ / NG_, 1,
            Bb, C1_, Tout, tt);
        T = Tout;
    }

    conv_tile_kernel<1, 64, 512, 64, 2><<<dim3(T / 64, Bc), 512, ldsz(C1_, 1), stream>>>(
        Bb, wt + wo.wxa, nullptr, nullptr, Cc, C1_, T, C1_, D_,
        nullptr, nullptr, nullptr, 0, 0, nullptr);
    gn_stats_kernel<<<Bc * NG_, 256, 0, stream>>>(Cc, st1, D_, T, NG_);

    conv_tile_kernel<5, 64, 512, 64, 1><<<dim3(T / 64, Bc), 512, ldsz(D_, 5), stream>>>(
        Cc, wt + wo.wxb, nullptr, nullptr, Cc + nbuf / 2, D_, T, 2, 2,
        st1, gxa_g, gxa_b, D_ / NG_, 1, nullptr);
    gn_stats_kernel<<<Bc * NG_, 256, 0, stream>>>(Cc + nbuf / 2, st2, D_, T, NG_);

    conv_tile_kernel<1, 128, 512, 64, 2><<<dim3(T / 64, Bc), 512, ldsz(D_, 1), stream>>>(
        Cc + nbuf / 2, wt + wo.wxc, nullptr, nullptr, A, D_, T, D_, C1_,
        st2, gxb_g, gxb_b, D_ / NG_, 1, nullptr);
    gn_stats_kernel<<<Bc * NG_, 256, 0, stream>>>(A, st3, C1_, T, NG_);

    {
        int Tout = T / 2;
        long tt = (long)Bc * C1_ * Tout;
        pool_fused_kernel<<<nblk(tt), 256, 0, stream>>>(
            A, st3, gxc_g, gxc_b, C1_ / NG_,
            Bb, nullptr, nullptr, nullptr, 0, 0,
            Cc, C1_, Tout, tt);
        T = Tout;
    }

    conv_tile_kernel<3, 64, 512, 64, 1><<<dim3(T / 64, Bc), 512, ldsz(C1_, 3), stream>>>(
        Cc, wt + wo.w2, bn2_g, bn2_b, Bb, C1_, T, C1_, C2_,
        nullptr, nullptr, nullptr, 0, 0, nullptr);

    // ============ VQ ============  (Bb -> hq in A)
    {
        int NP = Bc * T;
        vq_kernel<<<NP / 64, 256, 0, stream>>>(Bb, embed, wn, A, lossbuf, T);
    }

    // ============ decoder ============
    conv_tile_kernel<3, 128, 512, 64, 1><<<dim3(T / 64, Bc), 512, ldsz(C2_, 3), stream>>>(
        A, wt + wo.wd2, nullptr, nullptr, Bb, C2_, T, C2_, C1_,
        nullptr, nullptr, nullptr, 0, 0, nullptr);
    gn_stats_kernel<<<Bc * NG_, 256, 0, stream>>>(Bb, st4, C1_, T, NG_);

    {
        long tt = (long)Bc * C1_ * T;
        up_fused_kernel<<<nblk(tt), 256, 0, stream>>>(
            Bb, st4, gd2_g, gd2_b, C1_ / NG_, nullptr, Cc, C1_, T, tt);
        T *= 2;
    }

    conv_mfma5_kernel<<<dim3(T / 64, Bc), 256, 0, stream>>>(
        Cc, wbA, A, T, nullptr, nullptr, nullptr, 0);
    gn_stats_kernel<<<Bc * NG_, 256, 0, stream>>>(A, st5, C1_, T, NG_);

    conv_mfma5_kernel<<<dim3(T / 64, Bc), 256, 0, stream>>>(
        A, wbB, Bb, T, st5, gd1a_g, gd1a_b, C1_ / NG_);
    gn_stats_kernel<<<Bc * NG_, 256, 0, stream>>>(Bb, st6, C1_, T, NG_);

    {
        long tt = (long)Bc * C1_ * T;
        up_fused_kernel<<<nblk(tt), 256, 0, stream>>>(
            Bb, st6, gd1b_g, gd1b_b, C1_ / NG_, Cc, A, C1_, T, tt);
        T *= 2;
    }

    conv_mfma5_kernel<<<dim3(T / 64, Bc), 256, 0, stream>>>(
        A, wbA, Cc, T, nullptr, nullptr, nullptr, 0);
    gn_stats_kernel<<<Bc * NG_, 256, 0, stream>>>(Cc, st5, C1_, T, NG_);

    conv_mfma5_kernel<<<dim3(T / 64, Bc), 256, 0, stream>>>(
        Cc, wbB, Bb, T, st5, gd1a_g, gd1a_b, C1_ / NG_);
    gn_stats_kernel<<<Bc * NG_, 256, 0, stream>>>(Bb, st6, C1_, T, NG_);

    conv_tile_kernel<7, 4, 256, 64, 1><<<dim3(T / 64, Bc), 256, ldsz(C1_, 7), stream>>>(
        Bb, wt + wo.wd0, nullptr, bd0, out, C1_, T, C1_, ORG_,
        st6, gd1b_g, gd1b_b, C1_ / NG_, 1, A);
}

extern "C" void kernel_launch(void* const* d_in, const int* in_sizes, int n_in,
                              void* d_out, int out_size, void* d_ws, size_t ws_size,
                              hipStream_t stream) {
    const float* x = (const float*)d_in[0];
    const float* W[27];
    for (int i = 0; i < 27; ++i) W[i] = (const float*)d_in[i + 1];

    float* out = (float*)d_out;
    const WT wo = wt_offsets();

    // workspace: [wT f32 pool | bf16 MFMA weights | wnorm | stats | loss | A | B | C]
    const long WT_F32   = 262144;
    const long WB_F32   = 2 * 81920 / 2;
    const long FIXED = WT_F32 + WB_F32 + 1024 + 8 * 2048 + 64;
    int Bc = 0;
    for (int cand = B_; cand >= 1; cand >>= 1) {
        size_t need = ((size_t)FIXED + (size_t)3 * cand * C1_ * L_) * sizeof(float);
        if (need <= ws_size) { Bc = cand; break; }
    }
    if (Bc == 0) return;

    float* wt            = (float*)d_ws;
    unsigned short* wbA  = (unsigned short*)(wt + WT_F32);
    unsigned short* wbB  = wbA + 81920;
    float* wn            = wt + WT_F32 + WB_F32;
    float* st            = wn + 1024;
    float* lossbuf       = st + 8 * 2048;
    const long nbuf = (long)Bc * C1_ * L_;
    float* A  = lossbuf + 64;
    float* Bb = A + nbuf;
    float* Cc = Bb + nbuf;

    const int D_ = C1_ / 2;

    auto prep = [&](const float* w, long off, int CO, int cig, int K,
                    int so, int si, int sk, int koff) {
        int total = cig * K * CO;
        wprep_kernel<<<(total + 255) / 256, 256, 0, stream>>>(
            w, wt + off, CO, cig, K, so, si, sk, koff);
    };
    prep(W[0],  wo.w0,   C1_, ORG_, 7, ORG_ * 7, 7,        1,  0);
    prep(W[3],  wo.wxa,  D_,  C1_,  1, C1_,      1,        1,  0);
    prep(W[6],  wo.wxb,  D_,  2,    5, 2 * 5,    5,        1,  0);
    prep(W[9],  wo.wxc,  C1_, D_,   1, D_,       1,        1,  0);
    prep(W[12], wo.w2,   C2_, C1_,  3, C1_ * 3,  3,        1,  0);
    prep(W[16], wo.wd2,  C1_, C2_,  3, 3,        C1_ * 3, -1,  2);
    prep(W[25], wo.wd0,  ORG_, C1_, 7, 7,        ORG_ * 7, -1, 6);
    wprep_mfma_kernel<<<81920 / 256, 256, 0, stream>>>(W[19], wbA);  // wd1a
    wprep_mfma_kernel<<<81920 / 256, 256, 0, stream>>>(W[22], wbB);  // wd1b
    wnorm_kernel<<<(VQN_ + 255) / 256, 256, 0, stream>>>(W[15], wn);

    zero_kernel<<<1, 1, 0, stream>>>(lossbuf);

    for (int b0 = 0; b0 < B_; b0 += Bc) {
        const float* xc = x + (long)b0 * ORG_ * L_;
        float* outc = out + (long)b0 * ORG_ * L_;
        run_chunk(xc, W, wt, wo, wbA, wbB, wn, outc, A, Bb, Cc, st, lossbuf, Bc, nbuf, stream);
    }

    {
        float invNP = 1.f / (float)(B_ * (L_ / 4));  // N = 65536
        finalize_kernel<<<1, 1, 0, stream>>>(lossbuf, out, invNP, (long)out_size - 2);
    }
}

// Round 7
// 2595.570 us; speedup vs baseline: 1.0371x; 1.0371x over previous
//
#include <hip/hip_runtime.h>
#include <math.h>

// ---------------- constants ----------------
static constexpr int B_   = 128;
static constexpr int ORG_ = 4;
static constexpr int L_   = 2048;
static constexpr int C1_  = 128;
static constexpr int C2_  = 64;
static constexpr int NG_  = 8;
static constexpr int VQD_ = 64;
static constexpr int VQN_ = 1024;

typedef __attribute__((ext_vector_type(8))) short bf16x8;
typedef __attribute__((ext_vector_type(4))) float f32x4;

__device__ __forceinline__ float selu_f(float x) {
    const float scale = 1.0507009873554805f;
    const float alpha = 1.6732632423543772f;
    return scale * (x > 0.f ? x : alpha * expm1f(x));
}
__device__ __forceinline__ unsigned short f2bf(float x) {
    unsigned u = __float_as_uint(x);
    u = (u + 0x7FFFu + ((u >> 16) & 1u)) >> 16;
    return (unsigned short)u;
}

// ---------------- weight prep (f32 direct-conv layout) ----------------
__global__ void wprep_kernel(const float* __restrict__ w, float* __restrict__ wT,
                             int CO, int cig, int K, int so, int si, int sk, int koff)
{
    int idx = blockIdx.x * 256 + threadIdx.x;
    int total = cig * K * CO;
    if (idx >= total) return;
    int o = idx % CO;
    int r = idx / CO;
    int i = r / K, k = r % K;
    wT[idx] = w[(long)o * so + (long)i * si + (long)k * sk + koff];
}

// ---------------- weight prep (MFMA bf16 layout) for tconv 128x128 K=5 ----------------
// wb[((k*16 + ic*4 + ig)*128 + o)*8 + j] = bf16( w[i][o][4-k] ), i = ic*32 + ig*8 + j
__global__ void wprep_mfma_kernel(const float* __restrict__ w, unsigned short* __restrict__ wb)
{
    int idx = blockIdx.x * 256 + threadIdx.x;   // total 81920
    if (idx >= 5 * 16 * 128 * 8) return;
    int j  = idx & 7;
    int o  = (idx >> 3) & 127;
    int kk = idx >> 10;          // 0..79
    int ig = kk & 3, ic = (kk >> 2) & 3, k = kk >> 4;
    int i  = ic * 32 + ig * 8 + j;
    wb[idx] = f2bf(w[(long)i * (128 * 5) + o * 5 + (4 - k)]);
}

// ---------------- LDS-tiled f32 conv with optional fused input transform ----------------
template<int K, int CO, int NTHR, int TT, int OT>
__global__ __launch_bounds__(NTHR) void conv_tile_kernel(
    const float* __restrict__ in, const float* __restrict__ wT,
    const float* __restrict__ scale, const float* __restrict__ bias,
    float* __restrict__ out,
    int CI, int T, int cig, int cog,
    const float* __restrict__ ist, const float* __restrict__ ig,
    const float* __restrict__ ibt, int icpg, int iselu,
    const float* __restrict__ res)
{
    constexpr int P    = (K - 1) / 2;
    constexpr int SPAN = TT + K - 1;
    constexpr int RS   = (SPAN + 3) & ~3;
    constexpr int NO   = CO / OT;
    constexpr int NT   = (CO * TT) / (NTHR * OT);
    constexpr int XW   = NT + K - 1;
    extern __shared__ float lds[];

    const int tile = blockIdx.x;
    const int b    = blockIdx.y;
    const int t0g  = tile * TT;
    const float* inb = in + (long)b * CI * T;

    for (int idx = threadIdx.x; idx < CI * SPAN; idx += NTHR) {
        int c = idx / SPAN, j = idx % SPAN;
        int tt = t0g + j - P;
        float v = 0.f;
        if (tt >= 0 && tt < T) {
            v = inb[(long)c * T + tt];
            if (ist) {
                const float* s = &ist[2 * (b * NG_ + c / icpg)];
                v = (v - s[0]) * s[1] * ig[c] + ibt[c];
                if (res) v += res[((long)b * CI + c) * T + tt];
                if (iselu) v = selu_f(v);
            }
        }
        lds[c * RS + j] = v;
    }
    __syncthreads();

    const int o0   = (threadIdx.x % NO) * OT;
    const int slot = threadIdx.x / NO;
    const int t0   = slot * NT;
    const int g    = o0 / cog;
    const float* wrow = wT + o0;

    float acc[OT][NT];
#pragma unroll
    for (int oo = 0; oo < OT; ++oo)
#pragma unroll
        for (int u = 0; u < NT; ++u) acc[oo][u] = 0.f;

    for (int i = 0; i < cig; ++i) {
        const int irow = g * cig + i;
        float xin[(XW + 3) & ~3];
        if constexpr (NT % 4 == 0) {
            constexpr int X4 = (XW + 3) / 4;
            const float4* l4 = reinterpret_cast<const float4*>(&lds[irow * RS + t0]);
#pragma unroll
            for (int j = 0; j < X4; ++j) {
                float4 v = l4[j];
                xin[4 * j]     = v.x;
                xin[4 * j + 1] = v.y;
                xin[4 * j + 2] = v.z;
                xin[4 * j + 3] = v.w;
            }
        } else {
#pragma unroll
            for (int j = 0; j < XW; ++j) xin[j] = lds[irow * RS + t0 + j];
        }
        float wk[OT][K];
#pragma unroll
        for (int oo = 0; oo < OT; ++oo)
#pragma unroll
            for (int k = 0; k < K; ++k) wk[oo][k] = wrow[(i * K + k) * CO + oo];
#pragma unroll
        for (int oo = 0; oo < OT; ++oo)
#pragma unroll
            for (int u = 0; u < NT; ++u)
#pragma unroll
                for (int k = 0; k < K; ++k)
                    acc[oo][u] = fmaf(xin[u + k], wk[oo][k], acc[oo][u]);
    }

#pragma unroll
    for (int oo = 0; oo < OT; ++oo) {
        const int o = o0 + oo;
        const float sc = scale ? scale[o] : 1.f;
        const float bi = bias  ? bias[o]  : 0.f;
        float* ob = out + ((long)b * CO + o) * T + t0g + t0;
#pragma unroll
        for (int u = 0; u < NT; ++u) ob[u] = acc[oo][u] * sc + bi;
    }
}

// ---------------- MFMA bf16 conv: CI=128, CO=128, K=5 (decoder deres1) ----------------
__global__ __launch_bounds__(256) void conv_mfma5_kernel(
    const float* __restrict__ in, const unsigned short* __restrict__ wb,
    float* __restrict__ out, int T,
    const float* __restrict__ ist, const float* __restrict__ ig_,
    const float* __restrict__ ibt, int icpg)
{
    constexpr int SPAN = 68, RSI = 136;
    __shared__ unsigned short xlds[SPAN * RSI];   // 18.5 KB

    const int t0g = blockIdx.x * 64;
    const int b   = blockIdx.y;
    const float* inb = in + (long)b * 128 * T;

    for (int idx = threadIdx.x; idx < 128 * SPAN; idx += 256) {
        int i = idx / SPAN, j = idx % SPAN;
        int tt = t0g + j - 2;
        float v = 0.f;
        if (tt >= 0 && tt < T) {
            v = inb[(long)i * T + tt];
            if (ist) {
                const float* s = &ist[2 * (b * NG_ + i / icpg)];
                v = selu_f((v - s[0]) * s[1] * ig_[i] + ibt[i]);
            }
        }
        xlds[j * RSI + i] = f2bf(v);
    }
    __syncthreads();

    const int lane = threadIdx.x & 63;
    const int wid  = threadIdx.x >> 6;
    const int tw   = wid * 16;
    const int mr   = lane & 15;
    const int kg   = lane >> 4;

    f32x4 acc[8];
#pragma unroll
    for (int ot = 0; ot < 8; ++ot) acc[ot] = (f32x4){0.f, 0.f, 0.f, 0.f};

#pragma unroll
    for (int k = 0; k < 5; ++k) {
#pragma unroll
        for (int ic = 0; ic < 4; ++ic) {
            bf16x8 a = *(const bf16x8*)&xlds[(tw + mr + k) * RSI + ic * 32 + kg * 8];
            const unsigned short* wp = wb + (((k * 16 + ic * 4 + kg) * 128) + mr) * 8;
#pragma unroll
            for (int ot = 0; ot < 8; ++ot) {
                bf16x8 bfr = *(const bf16x8*)(wp + ot * 16 * 8);
                acc[ot] = __builtin_amdgcn_mfma_f32_16x16x32_bf16(a, bfr, acc[ot], 0, 0, 0);
            }
        }
    }

#pragma unroll
    for (int ot = 0; ot < 8; ++ot) {
        int o = ot * 16 + mr;
        float4 v = make_float4(acc[ot][0], acc[ot][1], acc[ot][2], acc[ot][3]);
        *(float4*)&out[((long)b * 128 + o) * T + t0g + tw + kg * 4] = v;
    }
}

// ---------------- GroupNorm stats ----------------
__global__ __launch_bounds__(256) void gn_stats_kernel(
    const float* __restrict__ x, float* __restrict__ stats,
    int C, int T, int G)
{
    const int bg = blockIdx.x;
    const int cpg = C / G;
    const int b = bg / G, g = bg % G;
    const float* base = x + ((long)b * C + (long)g * cpg) * T;
    const long n4 = (long)cpg * T / 4;
    const float4* b4 = (const float4*)base;
    float s = 0.f, ss = 0.f;
    for (long i = threadIdx.x; i < n4; i += blockDim.x) {
        float4 v = b4[i];
        s += v.x + v.y + v.z + v.w;
        ss += v.x * v.x + v.y * v.y + v.z * v.z + v.w * v.w;
    }
#pragma unroll
    for (int off = 32; off; off >>= 1) {
        s  += __shfl_down(s, off);
        ss += __shfl_down(ss, off);
    }
    __shared__ float sh_s[4], sh_ss[4];
    const int wid = threadIdx.x >> 6, lane = threadIdx.x & 63;
    if (lane == 0) { sh_s[wid] = s; sh_ss[wid] = ss; }
    __syncthreads();
    if (threadIdx.x == 0) {
        float S = 0.f, SS = 0.f;
        for (int i = 0; i < 4; ++i) { S += sh_s[i]; SS += sh_ss[i]; }
        float inv_n = 1.f / (float)((long)cpg * T);
        float mu  = S * inv_n;
        float var = SS * inv_n - mu * mu;
        stats[2 * bg]     = mu;
        stats[2 * bg + 1] = rsqrtf(var + 1e-5f);
    }
}

// ---------------- fused: out = maxpool2( selu( T1(x) + T2(r) ) ) ----------------
__global__ __launch_bounds__(256) void pool_fused_kernel(
    const float* __restrict__ x, const float* __restrict__ xst,
    const float* __restrict__ xg, const float* __restrict__ xb, int xcpg,
    const float* __restrict__ r, const float* __restrict__ rst,
    const float* __restrict__ rg, const float* __restrict__ rb, int rcpg, int rselu,
    float* __restrict__ out, int C, int Tout, long total)
{
    for (long idx = blockIdx.x * (long)blockDim.x + threadIdx.x; idx < total;
         idx += (long)gridDim.x * blockDim.x) {
        const int to = (int)(idx % Tout);
        const int c  = (int)((idx / Tout) % C);
        const int b  = (int)(idx / ((long)Tout * C));
        const long base = ((long)b * C + c) * (2 * Tout);
        const float* sx = &xst[2 * (b * NG_ + c / xcpg)];
        const float xgc = sx[1] * xg[c], xbc = xb[c] - sx[0] * sx[1] * xg[c];
        float rgc = 1.f, rbc = 0.f;
        if (rst) {
            const float* sr = &rst[2 * (b * NG_ + c / rcpg)];
            rgc = sr[1] * rg[c]; rbc = rb[c] - sr[0] * sr[1] * rg[c];
        }
        float f[2];
#pragma unroll
        for (int q = 0; q < 2; ++q) {
            long t = base + 2 * to + q;
            float rv = r[t] * rgc + rbc;
            if (rst && rselu) rv = selu_f(rv);
            f[q] = selu_f(x[t] * xgc + xbc + rv);
        }
        out[((long)b * C + c) * Tout + to] = fmaxf(f[0], f[1]);
    }
}

// ---------------- fused: out = upsample2( selu( T(x) [+ res] ) ) ----------------
__global__ __launch_bounds__(256) void up_fused_kernel(
    const float* __restrict__ x, const float* __restrict__ xst,
    const float* __restrict__ xg, const float* __restrict__ xb, int xcpg,
    const float* __restrict__ res,
    float* __restrict__ out, int C, int Tin, long total)
{
    for (long idx = blockIdx.x * (long)blockDim.x + threadIdx.x; idx < total;
         idx += (long)gridDim.x * blockDim.x) {
        const int t = (int)(idx % Tin);
        const int c = (int)((idx / Tin) % C);
        const int b = (int)(idx / ((long)Tin * C));
        const float* s = &xst[2 * (b * NG_ + c / xcpg)];
        float v = (x[idx] - s[0]) * s[1] * xg[c] + xb[c];
        if (res) v += res[idx];
        v = selu_f(v);
        float2* o2 = (float2*)(out + (((long)b * C + c) * Tin + t) * 2);
        *o2 = make_float2(v, v);
    }
}

// ---------------- VQ ----------------
__global__ void wnorm_kernel(const float* __restrict__ codes, float* __restrict__ wn)
{
    int j = blockIdx.x * 256 + threadIdx.x;
    if (j >= VQN_) return;
    const float* c = codes + (long)j * VQD_;
    float s = 0.f;
#pragma unroll
    for (int i = 0; i < VQD_; ++i) s = fmaf(c[i], c[i], s);
    wn[j] = s;
}

// VQ v4: 32 points x 8 code-slices of 128 per 256-thread block (1024 blocks/chunk).
// __launch_bounds__(256,4) caps VGPR at 128 so z[64] stays register-resident.
// Dot chain, scan order, strict-< tie-breaking identical to r5/r6 -> argmin bit-identical.
// hq written cooperatively (t-coalesced); loss recomputed from f32 h (no runtime z index).
__global__ __launch_bounds__(256, 4) void vq_kernel(
    const float* __restrict__ h, const float* __restrict__ codes,
    const float* __restrict__ wn, float* __restrict__ hq, float* __restrict__ loss,
    int T)
{
    const int p  = threadIdx.x & 31;   // point in block
    const int cs = threadIdx.x >> 5;   // code slice 0..7
    const int n0 = blockIdx.x * 32;
    const int b  = n0 / T;             // uniform per block (T % 32 == 0)
    const int tb = n0 % T;
    const int t  = tb + p;

    float z[VQD_];
#pragma unroll
    for (int c = 0; c < VQD_; ++c) z[c] = h[((long)b * VQD_ + c) * T + t];

    float best = 3.4e38f;
    int bj = cs * 128;
    for (int j = cs * 128; j < cs * 128 + 128; ++j) {
        const float4* cw4 = (const float4*)(codes + (long)j * VQD_);
        float dot = 0.f;
#pragma unroll
        for (int q = 0; q < VQD_ / 4; ++q) {
            float4 w4 = cw4[q];
            dot = fmaf(z[4 * q],     w4.x, dot);
            dot = fmaf(z[4 * q + 1], w4.y, dot);
            dot = fmaf(z[4 * q + 2], w4.z, dot);
            dot = fmaf(z[4 * q + 3], w4.w, dot);
        }
        float scv = wn[j] - 2.f * dot;
        if (scv < best) { best = scv; bj = j; }
    }

    __shared__ float sb[8][32];
    __shared__ int   sj[8][32];
    __shared__ int   sbj[32];
    sb[cs][p] = best; sj[cs][p] = bj;
    __syncthreads();
    if (cs == 0) {
#pragma unroll
        for (int s = 1; s < 8; ++s)
            if (sb[s][p] < best) { best = sb[s][p]; bj = sj[s][p]; }
        sbj[p] = bj;
    }
    __syncthreads();

    // cooperative hq write (t-coalesced) + loss from f32 h
    float l = 0.f;
#pragma unroll
    for (int r = 0; r < (VQD_ * 32) / 256; ++r) {
        int idx = r * 256 + threadIdx.x;
        int c  = idx >> 5, tl = idx & 31;
        int jj = sbj[tl];
        float wv = codes[(long)jj * VQD_ + c];
        long off = ((long)b * VQD_ + c) * T + tb + tl;
        hq[off] = wv;
        float df = h[off] - wv;
        l = fmaf(df, df, l);
    }
#pragma unroll
    for (int off = 32; off; off >>= 1) l += __shfl_down(l, off);
    if ((threadIdx.x & 63) == 0) atomicAdd(loss, l);
}

__global__ void zero_kernel(float* p) { p[0] = 0.f; }

__global__ void finalize_kernel(const float* __restrict__ loss, float* __restrict__ out,
                                float invNP, long off)
{
    float v = loss[0] * invNP;
    out[off]     = v;
    out[off + 1] = v;
}

// ---------------- host side ----------------
static inline int nblk(long total, int thr = 256, long cap = 262144) {
    long b = (total + thr - 1) / thr;
    if (b > cap) b = cap;
    if (b < 1) b = 1;
    return (int)b;
}
static inline int ldsz(int CI, int K, int TT = 64) {
    int span = TT + K - 1;
    int rs = (span + 3) & ~3;
    return CI * rs * 4;
}

struct WT {
    long w0, wxa, wxb, wxc, w2, wd2, wd0, total;
};
static WT wt_offsets() {
    WT o; long p = 0;
    o.w0   = p; p += (long)ORG_ * 7 * C1_;
    o.wxa  = p; p += (long)C1_ * 1 * (C1_ / 2);
    o.wxb  = p; p += 2L * 5 * (C1_ / 2);
    o.wxc  = p; p += (long)(C1_ / 2) * 1 * C1_;
    o.w2   = p; p += (long)C1_ * 3 * C2_;
    o.wd2  = p; p += (long)C2_ * 3 * C1_;
    o.wd0  = p; p += (long)C1_ * 7 * ORG_;
    o.total = p;
    return o;
}

static void run_chunk(const float* x, const float* const* W, const float* wt,
                      const WT& wo, const unsigned short* wbA, const unsigned short* wbB,
                      const float* wn, float* out,
                      float* A, float* Bb, float* Cc, float* st, float* lossbuf,
                      int Bc, long nbuf, hipStream_t stream)
{
    const float* g0_g  = W[1];
    const float* g0_b  = W[2];
    const float* gxa_g = W[4];
    const float* gxa_b = W[5];
    const float* gxb_g = W[7];
    const float* gxb_b = W[8];
    const float* gxc_g = W[10];
    const float* gxc_b = W[11];
    const float* bn2_g = W[13];
    const float* bn2_b = W[14];
    const float* embed = W[15];
    const float* gd2_g = W[17];
    const float* gd2_b = W[18];
    const float* gd1a_g= W[20];
    const float* gd1a_b= W[21];
    const float* gd1b_g= W[23];
    const float* gd1b_b= W[24];
    const float* bd0   = W[26];

    const int D_ = C1_ / 2;  // 64
    const int SLOT = 2048;
    float* st0 = st + 0 * SLOT;
    float* st1 = st + 1 * SLOT;
    float* st2 = st + 2 * SLOT;
    float* st3 = st + 3 * SLOT;
    float* st4 = st + 4 * SLOT;
    float* st5 = st + 5 * SLOT;
    float* st6 = st + 6 * SLOT;

    int T = L_;  // 2048

    // ============ encoder (all f32, bit-stable for VQ argmin) ============
    conv_tile_kernel<7, 128, 512, 64, 1><<<dim3(T / 64, Bc), 512, ldsz(ORG_, 7), stream>>>(
        x, wt + wo.w0, nullptr, nullptr, A, ORG_, T, ORG_, C1_,
        nullptr, nullptr, nullptr, 0, 0, nullptr);
    gn_stats_kernel<<<Bc * NG_, 256, 0, stream>>>(A, st0, C1_, T, NG_);

    conv_tile_kernel<1, 64, 512, 64, 2><<<dim3(T / 64, Bc), 512, ldsz(C1_, 1), stream>>>(
        A, wt + wo.wxa, nullptr, nullptr, Bb, C1_, T, C1_, D_,
        st0, g0_g, g0_b, C1_ / NG_, 1, nullptr);
    gn_stats_kernel<<<Bc * NG_, 256, 0, stream>>>(Bb, st1, D_, T, NG_);

    conv_tile_kernel<5, 64, 512, 64, 1><<<dim3(T / 64, Bc), 512, ldsz(D_, 5), stream>>>(
        Bb, wt + wo.wxb, nullptr, nullptr, Bb + nbuf / 2, D_, T, 2, 2,
        st1, gxa_g, gxa_b, D_ / NG_, 1, nullptr);
    gn_stats_kernel<<<Bc * NG_, 256, 0, stream>>>(Bb + nbuf / 2, st2, D_, T, NG_);

    conv_tile_kernel<1, 128, 512, 64, 2><<<dim3(T / 64, Bc), 512, ldsz(D_, 1), stream>>>(
        Bb + nbuf / 2, wt + wo.wxc, nullptr, nullptr, Cc, D_, T, D_, C1_,
        st2, gxb_g, gxb_b, D_ / NG_, 1, nullptr);
    gn_stats_kernel<<<Bc * NG_, 256, 0, stream>>>(Cc, st3, C1_, T, NG_);

    {
        int Tout = T / 2;
        long tt = (long)Bc * C1_ * Tout;
        pool_fused_kernel<<<nblk(tt), 256, 0, stream>>>(
            Cc, st3, gxc_g, gxc_b, C1_ / NG_,
            A, st0, g0_g, g0_b, C1_ / NG_, 1,
            Bb, C1_, Tout, tt);
        T = Tout;
    }

    conv_tile_kernel<1, 64, 512, 64, 2><<<dim3(T / 64, Bc), 512, ldsz(C1_, 1), stream>>>(
        Bb, wt + wo.wxa, nullptr, nullptr, Cc, C1_, T, C1_, D_,
        nullptr, nullptr, nullptr, 0, 0, nullptr);
    gn_stats_kernel<<<Bc * NG_, 256, 0, stream>>>(Cc, st1, D_, T, NG_);

    conv_tile_kernel<5, 64, 512, 64, 1><<<dim3(T / 64, Bc), 512, ldsz(D_, 5), stream>>>(
        Cc, wt + wo.wxb, nullptr, nullptr, Cc + nbuf / 2, D_, T, 2, 2,
        st1, gxa_g, gxa_b, D_ / NG_, 1, nullptr);
    gn_stats_kernel<<<Bc * NG_, 256, 0, stream>>>(Cc + nbuf / 2, st2, D_, T, NG_);

    conv_tile_kernel<1, 128, 512, 64, 2><<<dim3(T / 64, Bc), 512, ldsz(D_, 1), stream>>>(
        Cc + nbuf / 2, wt + wo.wxc, nullptr, nullptr, A, D_, T, D_, C1_,
        st2, gxb_g, gxb_b, D_ / NG_, 1, nullptr);
    gn_stats_kernel<<<Bc * NG_, 256, 0, stream>>>(A, st3, C1_, T, NG_);

    {
        int Tout = T / 2;
        long tt = (long)Bc * C1_ * Tout;
        pool_fused_kernel<<<nblk(tt), 256, 0, stream>>>(
            A, st3, gxc_g, gxc_b, C1_ / NG_,
            Bb, nullptr, nullptr, nullptr, 0, 0,
            Cc, C1_, Tout, tt);
        T = Tout;
    }

    conv_tile_kernel<3, 64, 512, 64, 1><<<dim3(T / 64, Bc), 512, ldsz(C1_, 3), stream>>>(
        Cc, wt + wo.w2, bn2_g, bn2_b, Bb, C1_, T, C1_, C2_,
        nullptr, nullptr, nullptr, 0, 0, nullptr);

    // ============ VQ ============  (Bb -> hq in A)
    {
        int NP = Bc * T;
        vq_kernel<<<NP / 32, 256, 0, stream>>>(Bb, embed, wn, A, lossbuf, T);
    }

    // ============ decoder ============
    conv_tile_kernel<3, 128, 512, 64, 1><<<dim3(T / 64, Bc), 512, ldsz(C2_, 3), stream>>>(
        A, wt + wo.wd2, nullptr, nullptr, Bb, C2_, T, C2_, C1_,
        nullptr, nullptr, nullptr, 0, 0, nullptr);
    gn_stats_kernel<<<Bc * NG_, 256, 0, stream>>>(Bb, st4, C1_, T, NG_);

    {
        long tt = (long)Bc * C1_ * T;
        up_fused_kernel<<<nblk(tt), 256, 0, stream>>>(
            Bb, st4, gd2_g, gd2_b, C1_ / NG_, nullptr, Cc, C1_, T, tt);
        T *= 2;
    }

    conv_mfma5_kernel<<<dim3(T / 64, Bc), 256, 0, stream>>>(
        Cc, wbA, A, T, nullptr, nullptr, nullptr, 0);
    gn_stats_kernel<<<Bc * NG_, 256, 0, stream>>>(A, st5, C1_, T, NG_);

    conv_mfma5_kernel<<<dim3(T / 64, Bc), 256, 0, stream>>>(
        A, wbB, Bb, T, st5, gd1a_g, gd1a_b, C1_ / NG_);
    gn_stats_kernel<<<Bc * NG_, 256, 0, stream>>>(Bb, st6, C1_, T, NG_);

    {
        long tt = (long)Bc * C1_ * T;
        up_fused_kernel<<<nblk(tt), 256, 0, stream>>>(
            Bb, st6, gd1b_g, gd1b_b, C1_ / NG_, Cc, A, C1_, T, tt);
        T *= 2;
    }

    conv_mfma5_kernel<<<dim3(T / 64, Bc), 256, 0, stream>>>(
        A, wbA, Cc, T, nullptr, nullptr, nullptr, 0);
    gn_stats_kernel<<<Bc * NG_, 256, 0, stream>>>(Cc, st5, C1_, T, NG_);

    conv_mfma5_kernel<<<dim3(T / 64, Bc), 256, 0, stream>>>(
        Cc, wbB, Bb, T, st5, gd1a_g, gd1a_b, C1_ / NG_);
    gn_stats_kernel<<<Bc * NG_, 256, 0, stream>>>(Bb, st6, C1_, T, NG_);

    conv_tile_kernel<7, 4, 256, 64, 1><<<dim3(T / 64, Bc), 256, ldsz(C1_, 7), stream>>>(
        Bb, wt + wo.wd0, nullptr, bd0, out, C1_, T, C1_, ORG_,
        st6, gd1b_g, gd1b_b, C1_ / NG_, 1, A);
}

extern "C" void kernel_launch(void* const* d_in, const int* in_sizes, int n_in,
                              void* d_out, int out_size, void* d_ws, size_t ws_size,
                              hipStream_t stream) {
    const float* x = (const float*)d_in[0];
    const float* W[27];
    for (int i = 0; i < 27; ++i) W[i] = (const float*)d_in[i + 1];

    float* out = (float*)d_out;
    const WT wo = wt_offsets();

    // workspace: [wT f32 pool | bf16 MFMA weights | wnorm | stats | loss | A | B | C]
    const long WT_F32   = 262144;
    const long WB_F32   = 2 * 81920 / 2;
    const long FIXED = WT_F32 + WB_F32 + 1024 + 8 * 2048 + 64;
    int Bc = 0;
    for (int cand = B_; cand >= 1; cand >>= 1) {
        size_t need = ((size_t)FIXED + (size_t)3 * cand * C1_ * L_) * sizeof(float);
        if (need <= ws_size) { Bc = cand; break; }
    }
    if (Bc == 0) return;

    float* wt            = (float*)d_ws;
    unsigned short* wbA  = (unsigned short*)(wt + WT_F32);
    unsigned short* wbB  = wbA + 81920;
    float* wn            = wt + WT_F32 + WB_F32;
    float* st            = wn + 1024;
    float* lossbuf       = st + 8 * 2048;
    const long nbuf = (long)Bc * C1_ * L_;
    float* A  = lossbuf + 64;
    float* Bb = A + nbuf;
    float* Cc = Bb + nbuf;

    const int D_ = C1_ / 2;

    auto prep = [&](const float* w, long off, int CO, int cig, int K,
                    int so, int si, int sk, int koff) {
        int total = cig * K * CO;
        wprep_kernel<<<(total + 255) / 256, 256, 0, stream>>>(
            w, wt + off, CO, cig, K, so, si, sk, koff);
    };
    prep(W[0],  wo.w0,   C1_, ORG_, 7, ORG_ * 7, 7,        1,  0);
    prep(W[3],  wo.wxa,  D_,  C1_,  1, C1_,      1,        1,  0);
    prep(W[6],  wo.wxb,  D_,  2,    5, 2 * 5,    5,        1,  0);
    prep(W[9],  wo.wxc,  C1_, D_,   1, D_,       1,        1,  0);
    prep(W[12], wo.w2,   C2_, C1_,  3, C1_ * 3,  3,        1,  0);
    prep(W[16], wo.wd2,  C1_, C2_,  3, 3,        C1_ * 3, -1,  2);
    prep(W[25], wo.wd0,  ORG_, C1_, 7, 7,        ORG_ * 7, -1, 6);
    wprep_mfma_kernel<<<81920 / 256, 256, 0, stream>>>(W[19], wbA);  // wd1a
    wprep_mfma_kernel<<<81920 / 256, 256, 0, stream>>>(W[22], wbB);  // wd1b
    wnorm_kernel<<<(VQN_ + 255) / 256, 256, 0, stream>>>(W[15], wn);

    zero_kernel<<<1, 1, 0, stream>>>(lossbuf);

    for (int b0 = 0; b0 < B_; b0 += Bc) {
        const float* xc = x + (long)b0 * ORG_ * L_;
        float* outc = out + (long)b0 * ORG_ * L_;
        run_chunk(xc, W, wt, wo, wbA, wbB, wn, outc, A, Bb, Cc, st, lossbuf, Bc, nbuf, stream);
    }

    {
        float invNP = 1.f / (float)(B_ * (L_ / 4));  // N = 65536
        finalize_kernel<<<1, 1, 0, stream>>>(lossbuf, out, invNP, (long)out_size - 2);
    }
}